// Round 1
// baseline (109.768 us; speedup 1.0000x reference)
//
#include <hip/hip_runtime.h>
#include <math.h>

#define BB 8
#define TQ 256
#define TV 512
#define DD 128
#define TI 4
#define LN_EPS 1e-3f

typedef float f4 __attribute__((ext_vector_type(4)));

// ---------------- Kernel 1: precompute tanh(context) and scale*tanh(context) --------
// B*TV*D = 524288 floats = 131072 float4s; grid 512x256
__global__ __launch_bounds__(256) void prep_kernel(const float* __restrict__ ctx,
                                                   const float* __restrict__ scale,
                                                   float* __restrict__ tc,
                                                   float* __restrict__ tcs) {
    int idx = blockIdx.x * 256 + threadIdx.x;      // float4 index
    const f4* c4 = (const f4*)ctx;
    const f4* s4 = (const f4*)scale;
    f4 c = c4[idx];
    f4 s = s4[idx & 31];                           // D/4 = 32 float4s per row
    f4 t, ts;
#pragma unroll
    for (int k = 0; k < 4; ++k) {
        float tv = tanhf(c[k]);
        t[k] = tv;
        ts[k] = tv * s[k];
    }
    ((f4*)tc)[idx] = t;
    ((f4*)tcs)[idx] = ts;
}

// ---------------- Kernel 2: fused scores + softmax + PV + residual + LayerNorm ------
// One block handles TI=4 query rows. 512 threads = 8 waves. Thread t owns j = t.
__global__ __launch_bounds__(512) void attn_kernel(const float* __restrict__ x,
                                                   const float* __restrict__ ctx,
                                                   const float* __restrict__ scale,
                                                   const float* __restrict__ gamma,
                                                   const float* __restrict__ beta,
                                                   const float* __restrict__ tc,
                                                   const float* __restrict__ tcs,
                                                   float* __restrict__ out) {
    __shared__ float xs[TI * DD];     // raw x rows (residual)        2KB
    __shared__ f4    txT[DD];         // [d] -> tanh(x) for 4 rows    2KB
    __shared__ f4    AT[DD];          // [d] -> scale*tanh(x) 4 rows  2KB
    __shared__ f4    wT[TV];          // [j] -> softmax weights 4 rows 8KB
    __shared__ float red[4 * TI * DD];// PV partials [g][r][d]        8KB
    __shared__ f4    mred[8];
    __shared__ f4    sred[8];
    __shared__ float lnred[8][2];

    const int t    = threadIdx.x;
    const int bg   = blockIdx.x;
    const int b    = bg >> 6;          // 64 blocks per batch
    const int i0   = (bg & 63) * TI;
    const int wv   = t >> 6;           // wave id 0..7
    const int lane = t & 63;

    // ---- setup: load x rows, tanh, stage transposed to LDS ----
    {
        int r = t >> 7, d = t & 127;
        float v  = x[(size_t)((b * TQ) + i0 + r) * DD + d];
        float sv = scale[d];
        float tv = tanhf(v);
        xs[r * DD + d] = v;
        txT[d][r] = tv;
        AT[d][r]  = sv * tv;
    }
    __syncthreads();

    // ---- phase 1: scores. acc[r] = sum_d scale*(tx+tc)/(1+tx*tc) ----
    float acc[TI] = {0.f, 0.f, 0.f, 0.f};
    {
        const f4* tcp  = (const f4*)(tc  + (size_t)(b * TV + t) * DD);
        const f4* tcsp = (const f4*)(tcs + (size_t)(b * TV + t) * DD);
#pragma unroll 4
        for (int d4 = 0; d4 < DD / 4; ++d4) {
            f4 c  = tcp[d4];
            f4 cs = tcsp[d4];
#pragma unroll
            for (int k = 0; k < 4; ++k) {
                int d = d4 * 4 + k;
                f4 tx4 = txT[d];   // LDS broadcast (uniform addr)
                f4 A4  = AT[d];
#pragma unroll
                for (int r = 0; r < TI; ++r) {
                    float num = A4[r] + cs[k];                 // scale*(tx+tc)
                    float den = fmaf(tx4[r], c[k], 1.0f);      // 1 + tx*tc
                    acc[r] = fmaf(num, __builtin_amdgcn_rcpf(den), acc[r]);
                }
            }
        }
    }

    // ---- phase 2: softmax over j = 0..511 (block-wide) ----
    f4 m;
#pragma unroll
    for (int r = 0; r < TI; ++r) m[r] = acc[r];
#pragma unroll
    for (int off = 32; off > 0; off >>= 1) {
#pragma unroll
        for (int r = 0; r < TI; ++r) m[r] = fmaxf(m[r], __shfl_xor(m[r], off));
    }
    if (lane == 0) mred[wv] = m;
    __syncthreads();
    f4 M = mred[0];
#pragma unroll
    for (int w = 1; w < 8; ++w) {
        f4 o = mred[w];
#pragma unroll
        for (int r = 0; r < TI; ++r) M[r] = fmaxf(M[r], o[r]);
    }
    f4 e;
#pragma unroll
    for (int r = 0; r < TI; ++r) e[r] = __expf(acc[r] - M[r]);
    f4 s = e;
#pragma unroll
    for (int off = 32; off > 0; off >>= 1) {
#pragma unroll
        for (int r = 0; r < TI; ++r) s[r] += __shfl_xor(s[r], off);
    }
    if (lane == 0) sred[wv] = s;
    __syncthreads();
    f4 S = sred[0];
#pragma unroll
    for (int w = 1; w < 8; ++w) {
        f4 o = sred[w];
#pragma unroll
        for (int r = 0; r < TI; ++r) S[r] += o[r];
    }
    f4 w4;
#pragma unroll
    for (int r = 0; r < TI; ++r) w4[r] = e[r] * __builtin_amdgcn_rcpf(S[r]);
    wT[t] = w4;
    __syncthreads();

    // ---- phase 3: attn_out[r][d] = sum_j w[r][j]*ctx[j][d] ----
    {
        const int g = t >> 7;     // j-group 0..3, 128 j each
        const int d = t & 127;
        const float* cp = ctx + (size_t)(b * TV + g * 128) * DD + d;
        f4 p = {0.f, 0.f, 0.f, 0.f};
#pragma unroll 4
        for (int jj = 0; jj < 128; ++jj) {
            f4 wj = wT[g * 128 + jj];    // LDS broadcast
            float cv = cp[(size_t)jj * DD];
#pragma unroll
            for (int r = 0; r < TI; ++r) p[r] = fmaf(wj[r], cv, p[r]);
        }
#pragma unroll
        for (int r = 0; r < TI; ++r) red[(g * TI + r) * DD + d] = p[r];
    }
    __syncthreads();

    // ---- phase 4: reduce partials, residual, LayerNorm, store ----
    {
        const int r = t >> 7;     // row 0..3
        const int d = t & 127;
        float attn = red[(0 * TI + r) * DD + d] + red[(1 * TI + r) * DD + d] +
                     red[(2 * TI + r) * DD + d] + red[(3 * TI + r) * DD + d];
        float y = xs[r * DD + d] + attn;
        float s1 = y, s2 = y * y;
#pragma unroll
        for (int off = 32; off > 0; off >>= 1) {
            s1 += __shfl_xor(s1, off);
            s2 += __shfl_xor(s2, off);
        }
        if (lane == 0) { lnred[wv][0] = s1; lnred[wv][1] = s2; }
        __syncthreads();
        float S1 = lnred[2 * r][0] + lnred[2 * r + 1][0];
        float S2 = lnred[2 * r][1] + lnred[2 * r + 1][1];
        float mu  = S1 * (1.0f / 128.0f);
        float var = S2 * (1.0f / 128.0f) - mu * mu;
        float inv = rsqrtf(var + LN_EPS);
        out[(size_t)((b * TQ) + i0 + r) * DD + d] = gamma[d] * (y - mu) * inv + beta[d];
    }
}

extern "C" void kernel_launch(void* const* d_in, const int* in_sizes, int n_in,
                              void* d_out, int out_size, void* d_ws, size_t ws_size,
                              hipStream_t stream) {
    const float* x     = (const float*)d_in[0];
    const float* ctx   = (const float*)d_in[1];
    const float* scale = (const float*)d_in[2];
    const float* gamma = (const float*)d_in[3];
    const float* beta  = (const float*)d_in[4];
    float* out = (float*)d_out;

    float* tc  = (float*)d_ws;                    // B*TV*D floats = 2MB
    float* tcs = tc + (size_t)BB * TV * DD;       // B*TV*D floats = 2MB

    prep_kernel<<<(BB * TV * DD / 4) / 256, 256, 0, stream>>>(ctx, scale, tc, tcs);
    attn_kernel<<<(BB * TQ) / TI, 512, 0, stream>>>(x, ctx, scale, gamma, beta, tc, tcs, out);
}

// Round 2
// 90.913 us; speedup vs baseline: 1.2074x; 1.2074x over previous
//
#include <hip/hip_runtime.h>
#include <math.h>

#define BB 8
#define TQ 256
#define TV 512
#define DD 128
#define TI 4
#define NT 1024
#define LN_EPS 1e-3f

typedef float f4 __attribute__((ext_vector_type(4)));

// ---------------- Kernel 1: F = exp(2*context) ----------------
// B*TV*D = 524288 floats = 131072 f4; grid 512 x 256
__global__ __launch_bounds__(256) void prep_kernel(const float* __restrict__ ctx,
                                                   float* __restrict__ F) {
    int idx = blockIdx.x * 256 + threadIdx.x;
    f4 c = ((const f4*)ctx)[idx];
    f4 r;
#pragma unroll
    for (int k = 0; k < 4; ++k) r[k] = __expf(2.0f * c[k]);
    ((f4*)F)[idx] = r;
}

// ---------------- Kernel 2: fused scores + softmax + PV + residual + LN ----
// 1024 threads (16 waves), TI=4 query rows per block, grid = 512 (2 blocks/CU).
// score'[j] = sum_d (-2 s_d) / (1 + E[i,d]*F[j,d]);  softmax-equivalent to ref.
__global__ __launch_bounds__(NT, 8) void attn_kernel(const float* __restrict__ x,
                                                     const float* __restrict__ ctx,
                                                     const float* __restrict__ scale,
                                                     const float* __restrict__ gamma,
                                                     const float* __restrict__ beta,
                                                     const float* __restrict__ F,
                                                     float* __restrict__ out) {
    __shared__ float xs[TI * DD];      // residual rows                  2KB
    __shared__ f4    txE[DD];          // [d] -> e^{2x} for 4 rows       2KB
    __shared__ float s2n[DD];          // -2*scale[d]                    0.5KB
    __shared__ f4    pacc[TV];         // h=1 partial scores             8KB
    __shared__ f4    wT[TV];           // softmax weights per j          8KB
    __shared__ float red[8][TI][DD];   // PV partials                    16KB
    __shared__ f4    mred[8];
    __shared__ f4    sred[8];
    __shared__ float lnred[8][2];

    const int t  = threadIdx.x;
    const int bg = blockIdx.x;
    // bijective XCD swizzle: 512 blocks, 8 XCDs, 64 blocks per XCD -> XCD k owns batch k
    const int wg   = (bg & 7) * 64 + (bg >> 3);
    const int b    = wg >> 6;
    const int i0   = (wg & 63) * TI;
    const int wv   = t >> 6;
    const int lane = t & 63;

    // ---- setup: x rows -> E = e^{2x} transposed in LDS; s2n; residual copy ----
    if (t < TI * DD) {
        int r = t >> 7, d = t & 127;
        float v = x[(size_t)(b * TQ + i0 + r) * DD + d];
        xs[t] = v;
        txE[d][r] = __expf(2.0f * v);
    }
    if (t >= 512 && t < 512 + DD) s2n[t - 512] = -2.0f * scale[t - 512];
    __syncthreads();

    // ---- phase 1: partial scores; thread t owns (j = t&511, d-half h = t>>9) ----
    const int j = t & 511;
    const int h = t >> 9;
    f4 acc = {0.f, 0.f, 0.f, 0.f};
    {
        const f4* Fp = (const f4*)(F + (size_t)(b * TV + j) * DD + h * 64);
#pragma unroll 2
        for (int d4 = 0; d4 < 16; ++d4) {
            f4 Fv = Fp[d4];
#pragma unroll
            for (int k = 0; k < 4; ++k) {
                const int d = h * 64 + d4 * 4 + k;
                f4 E = txE[d];          // LDS broadcast b128
                float sn = s2n[d];      // LDS broadcast b32
                f4 den, u;
#pragma unroll
                for (int r = 0; r < TI; ++r) den[r] = fmaf(E[r], Fv[k], 1.0f);
#pragma unroll
                for (int r = 0; r < TI; ++r) u[r] = __builtin_amdgcn_rcpf(den[r]);
#pragma unroll
                for (int r = 0; r < TI; ++r) acc[r] = fmaf(sn, u[r], acc[r]);
            }
        }
    }
    if (h == 1) pacc[j] = acc;
    __syncthreads();
    if (h == 0) {
        f4 o = pacc[j];
#pragma unroll
        for (int r = 0; r < TI; ++r) acc[r] += o[r];
    }

    // ---- phase 2: block softmax over j (h==0 threads hold full scores) ----
    f4 m = acc;
#pragma unroll
    for (int off = 32; off > 0; off >>= 1) {
#pragma unroll
        for (int r = 0; r < TI; ++r) m[r] = fmaxf(m[r], __shfl_xor(m[r], off));
    }
    if (lane == 0 && wv < 8) mred[wv] = m;
    __syncthreads();
    f4 M = mred[0];
#pragma unroll
    for (int w = 1; w < 8; ++w) {
        f4 o = mred[w];
#pragma unroll
        for (int r = 0; r < TI; ++r) M[r] = fmaxf(M[r], o[r]);
    }
    f4 e;
#pragma unroll
    for (int r = 0; r < TI; ++r) e[r] = __expf(acc[r] - M[r]);
    f4 s = e;
#pragma unroll
    for (int off = 32; off > 0; off >>= 1) {
#pragma unroll
        for (int r = 0; r < TI; ++r) s[r] += __shfl_xor(s[r], off);
    }
    if (lane == 0 && wv < 8) sred[wv] = s;
    __syncthreads();
    f4 S = sred[0];
#pragma unroll
    for (int w = 1; w < 8; ++w) {
        f4 o = sred[w];
#pragma unroll
        for (int r = 0; r < TI; ++r) S[r] += o[r];
    }
    if (h == 0) {
        f4 w4;
#pragma unroll
        for (int r = 0; r < TI; ++r) w4[r] = e[r] * __builtin_amdgcn_rcpf(S[r]);
        wT[j] = w4;
    }
    __syncthreads();

    // ---- phase 3: attn_out[r][d] = sum_j w[r][j]*ctx[j][d]; 8 j-groups of 64 ----
    {
        const int g = t >> 7;       // 0..7
        const int d = t & 127;
        const float* cp = ctx + (size_t)(b * TV + g * 64) * DD + d;
        f4 p = {0.f, 0.f, 0.f, 0.f};
#pragma unroll 4
        for (int jj = 0; jj < 64; ++jj) {
            f4 wj = wT[g * 64 + jj];            // LDS broadcast
            float cv = cp[(size_t)jj * DD];     // coalesced
#pragma unroll
            for (int r = 0; r < TI; ++r) p[r] = fmaf(wj[r], cv, p[r]);
        }
#pragma unroll
        for (int r = 0; r < TI; ++r) red[g][r][d] = p[r];
    }
    __syncthreads();

    // ---- phase 4: reduce partials, residual, LayerNorm, store ----
    {
        const int r = t >> 7;       // valid for t<512
        const int d = t & 127;
        float y = 0.f;
        if (t < 512) {
            float attn = 0.f;
#pragma unroll
            for (int g = 0; g < 8; ++g) attn += red[g][r][d];
            y = xs[r * DD + d] + attn;
        }
        float s1 = y, s2 = y * y;
#pragma unroll
        for (int off = 32; off > 0; off >>= 1) {
            s1 += __shfl_xor(s1, off);
            s2 += __shfl_xor(s2, off);
        }
        if (lane == 0 && wv < 8) { lnred[wv][0] = s1; lnred[wv][1] = s2; }
        __syncthreads();
        if (t < 512) {
            float S1 = lnred[2 * r][0] + lnred[2 * r + 1][0];
            float S2 = lnred[2 * r][1] + lnred[2 * r + 1][1];
            float mu  = S1 * (1.0f / 128.0f);
            float var = S2 * (1.0f / 128.0f) - mu * mu;
            float inv = rsqrtf(var + LN_EPS);
            out[(size_t)(b * TQ + i0 + r) * DD + d] = gamma[d] * (y - mu) * inv + beta[d];
        }
    }
}

extern "C" void kernel_launch(void* const* d_in, const int* in_sizes, int n_in,
                              void* d_out, int out_size, void* d_ws, size_t ws_size,
                              hipStream_t stream) {
    const float* x     = (const float*)d_in[0];
    const float* ctx   = (const float*)d_in[1];
    const float* scale = (const float*)d_in[2];
    const float* gamma = (const float*)d_in[3];
    const float* beta  = (const float*)d_in[4];
    float* out = (float*)d_out;

    float* F = (float*)d_ws;   // B*TV*D floats = 2MB

    prep_kernel<<<(BB * TV * DD / 4) / 256, 256, 0, stream>>>(ctx, F);
    attn_kernel<<<(BB * TQ) / TI, NT, 0, stream>>>(x, ctx, scale, gamma, beta, F, out);
}